// Round 7
// baseline (163.069 us; speedup 1.0000x reference)
//
#include <hip/hip_runtime.h>
#include <hip/hip_bf16.h>

#define BT 4
#define TT 4096
#define DM 1024
#define DH 64
#define NRE 17
#define LOG2E 1.4426950408889634f

using bf16 = __hip_bfloat16;
typedef __attribute__((ext_vector_type(8))) short short8;
typedef __attribute__((ext_vector_type(4))) short short4v;
typedef __attribute__((ext_vector_type(4))) float float4v;

#define BC8(x) __builtin_bit_cast(short8, x)

static __device__ __forceinline__ short8 load8(const bf16* p) {
    return *reinterpret_cast<const short8*>(p);
}
static __device__ __forceinline__ short bfbits(float x) {
    return (short)__bfloat16_as_ushort(__float2bfloat16(x));
}
static __device__ __forceinline__ short8 pack8(float4v a, float4v b) {
    short8 r;
    r[0] = bfbits(a[0]); r[1] = bfbits(a[1]); r[2] = bfbits(a[2]); r[3] = bfbits(a[3]);
    r[4] = bfbits(b[0]); r[5] = bfbits(b[1]); r[6] = bfbits(b[2]); r[7] = bfbits(b[3]);
    return r;
}
static __device__ __forceinline__ void gload_lds16(const void* g, void* l) {
    __builtin_amdgcn_global_load_lds(
        (const __attribute__((address_space(1))) void*)g,
        (__attribute__((address_space(3))) void*)l, 16, 0, 0);
}
static __device__ __forceinline__ unsigned lds_addr(const void* p) {
    return (unsigned)(size_t)(const __attribute__((address_space(3))) void*)p;
}

// invisible-to-waitcnt-pass LDS fragment read (offset must be a literal string)
#define DSR(dst, addr, off) \
    asm volatile("ds_read_b128 %0, %1 offset:" off : "=v"(dst) : "v"(addr))

// ===========================================================================
// Swizzled global layouts (16B units, frag-major) — identical to prior rounds.
// ===========================================================================

__global__ __launch_bounds__(256) void w_prep(
    const float* __restrict__ Wq, const float* __restrict__ Wk,
    const float* __restrict__ Wv, bf16* __restrict__ Wswz)
{
    const unsigned g = blockIdx.x * 256 + threadIdx.x;   // < 24576
    const unsigned c    = g / 768;
    const unsigned rem  = g - c * 768;
    const unsigned pair = rem >> 3;
    const unsigned slot = rem & 7;
    const unsigned l    = slot ^ (pair & 7);
    const unsigned row  = 2 * pair + (l >> 2);
    const unsigned k    = 32 * c + (l & 3) * 8;
    const float* src = (row < 64) ? &Wq[(size_t)row * DM + k]
                     : (row < 128) ? &Wk[(size_t)(row - 64) * DM + k]
                                   : &Wv[(size_t)(row - 128) * DM + k];
    float4v a = *reinterpret_cast<const float4v*>(src);
    float4v b = *reinterpret_cast<const float4v*>(src + 4);
    *reinterpret_cast<short8*>(&Wswz[(size_t)g * 8]) = pack8(a, b);
}

// ---------------------------------------------------------------------------
// Kernel 1: QKV GEMM. Unchanged (proven; not current bottleneck).
// ---------------------------------------------------------------------------
__global__ __launch_bounds__(256, 2) void qkv_gemm(
    const float* __restrict__ x, const bf16* __restrict__ Wswz,
    bf16* __restrict__ Qb, bf16* __restrict__ Kswz, bf16* __restrict__ Vswz)
{
    __shared__ __align__(16) float xs[2][2048];   // 2 x 8 KB  [row(32)][unit(16)]
    __shared__ __align__(16) short Wls[2][12288]; // 2 x 24 KB (2 swz chunks)

    const int w    = threadIdx.x >> 6;
    const int lane = threadIdx.x & 63;
    const int quad = lane >> 4;
    const int l16  = lane & 15;
    const int half = w & 1;
    const int colh = w >> 1;
    const int row0 = blockIdx.x * 32;

    float4v acc[6];
#pragma unroll
    for (int i = 0; i < 6; i++) acc[i] = (float4v)(0.f);

    auto stage = [&](int c, int p) {
#pragma unroll
        for (int j = 0; j < 2; j++) {
            const int call = 2 * w + j;
            const int row  = 4 * call + (lane >> 4);
            const int pu   = lane & 15;
            const int gu   = (pu & 8) | ((pu ^ row) & 7);
            gload_lds16(&x[(size_t)(row0 + row) * DM + c * 64 + gu * 4],
                        &xs[p][call * 256]);
        }
#pragma unroll
        for (int j = 0; j < 6; j++) {
            const int call = 6 * w + j;
            gload_lds16(&Wswz[(size_t)(2 * c) * 6144 + call * 512 + lane * 8],
                        &Wls[p][call * 512]);
        }
    };

    const unsigned xlds = lds_addr(&xs[0][0]);
    const unsigned wlds = lds_addr(&Wls[0][0]);
    const int R        = 16 * half + l16;
    const int lo3_0    = (2 * quad)     ^ (R & 7);
    const int lo3_1    = (2 * quad + 1) ^ (R & 7);
    const int pairBase = 48 * colh + (l16 >> 1);
    const int physW    = ((l16 & 1) * 4 + quad) ^ ((l16 >> 1) & 7);

    stage(0, 0);

    for (int c = 0; c < 16; c++) {
        const int p = c & 1;
        __syncthreads();
        if (c + 1 < 16) stage(c + 1, p ^ 1);

        const unsigned xb  = xlds + (unsigned)(p * 8192) + R * 64 * 4;
        const unsigned xa0 = xb + lo3_0 * 16;
        const unsigned xa1 = xb + lo3_1 * 16;
        const unsigned wa  = wlds + (unsigned)(p * 24576) + pairBase * 128 + physW * 16;

        float4v x00, x01, x10, x11;
        float4v w00, w01, w02, w03, w04, w05, w10, w11, w12, w13, w14, w15;
        DSR(x00, xa0, "0");   DSR(x10, xa0, "128");
        DSR(x01, xa1, "0");   DSR(x11, xa1, "128");
        DSR(w00, wa, "0");     DSR(w01, wa, "1024");  DSR(w02, wa, "2048");
        DSR(w03, wa, "3072");  DSR(w04, wa, "4096");  DSR(w05, wa, "5120");
        DSR(w10, wa, "12288"); DSR(w11, wa, "13312"); DSR(w12, wa, "14336");
        DSR(w13, wa, "15360"); DSR(w14, wa, "16384"); DSR(w15, wa, "17408");
        asm volatile("s_waitcnt lgkmcnt(0)"
            : "+v"(x00), "+v"(x01), "+v"(x10), "+v"(x11),
              "+v"(w00), "+v"(w01), "+v"(w02), "+v"(w03), "+v"(w04), "+v"(w05),
              "+v"(w10), "+v"(w11), "+v"(w12), "+v"(w13), "+v"(w14), "+v"(w15));

        short8 a0 = pack8(x00, x01);
        short8 a1 = pack8(x10, x11);
        acc[0] = __builtin_amdgcn_mfma_f32_16x16x32_bf16(a0, BC8(w00), acc[0], 0, 0, 0);
        acc[1] = __builtin_amdgcn_mfma_f32_16x16x32_bf16(a0, BC8(w01), acc[1], 0, 0, 0);
        acc[2] = __builtin_amdgcn_mfma_f32_16x16x32_bf16(a0, BC8(w02), acc[2], 0, 0, 0);
        acc[3] = __builtin_amdgcn_mfma_f32_16x16x32_bf16(a0, BC8(w03), acc[3], 0, 0, 0);
        acc[4] = __builtin_amdgcn_mfma_f32_16x16x32_bf16(a0, BC8(w04), acc[4], 0, 0, 0);
        acc[5] = __builtin_amdgcn_mfma_f32_16x16x32_bf16(a0, BC8(w05), acc[5], 0, 0, 0);
        acc[0] = __builtin_amdgcn_mfma_f32_16x16x32_bf16(a1, BC8(w10), acc[0], 0, 0, 0);
        acc[1] = __builtin_amdgcn_mfma_f32_16x16x32_bf16(a1, BC8(w11), acc[1], 0, 0, 0);
        acc[2] = __builtin_amdgcn_mfma_f32_16x16x32_bf16(a1, BC8(w12), acc[2], 0, 0, 0);
        acc[3] = __builtin_amdgcn_mfma_f32_16x16x32_bf16(a1, BC8(w13), acc[3], 0, 0, 0);
        acc[4] = __builtin_amdgcn_mfma_f32_16x16x32_bf16(a1, BC8(w14), acc[4], 0, 0, 0);
        acc[5] = __builtin_amdgcn_mfma_f32_16x16x32_bf16(a1, BC8(w15), acc[5], 0, 0, 0);
    }

    // ---- epilogue: Q direct; K/V through LDS images (alias xs) ----
    __syncthreads();
    short* Kimg = (short*)&xs[0][0];      // 4 KB (256 units)
    short* Vimg = Kimg + 2048;            // 4 KB
#pragma unroll
    for (int nt = 0; nt < 6; nt++) {
        const int cc = 96 * colh + 16 * nt + l16;          // 0..191
#pragma unroll
        for (int r = 0; r < 4; r++) {
            const int jl = 16 * half + 4 * quad + r;       // local row 0..31
            const short hb = bfbits(acc[nt][r]);
            if (cc < 64) {
                Qb[(size_t)(row0 + jl) * DH + cc] = __hip_bfloat16_raw{(unsigned short)hb};
            } else if (cc < 128) {
                const int k  = cc - 64;
                const int h  = k >> 5;
                const int q2 = (k & 31) >> 3;
                Kimg[((2 * half + h) * 64 + q2 * 16 + 4 * quad + r) * 8 + (k & 7)] = hb;
            } else {
                const int d  = cc - 128;
                const int dh = d >> 5;
                const int hi = (d >> 4) & 1;
                Vimg[((2 * half + dh) * 64 + quad * 16 + (d & 15)) * 8 + hi * 4 + r] = hb;
            }
        }
    }
    __syncthreads();
    {
        const int b_     = row0 >> 12;
        const int tile32 = (row0 & (TT - 1)) >> 5;
        const size_t base = ((size_t)(b_ * 512 + tile32 * 4)) * 512;  // elems
        const int u = threadIdx.x;                                    // 256 units
        *reinterpret_cast<short8*>(&Kswz[base + (size_t)u * 8]) =
            *reinterpret_cast<const short8*>(&Kimg[u * 8]);
        *reinterpret_cast<short8*>(&Vswz[base + (size_t)u * 8]) =
            *reinterpret_cast<const short8*>(&Vimg[u * 8]);
    }
}

// ---------------------------------------------------------------------------
// Kernel 2: flash causal attention — SPLIT-K pair blocks, 4 waves/SIMD.
// Grid = 4 batch x 64 pr x 2 halves = 512 blocks x 512 thr, 64KB LDS
// -> 2 blocks/CU -> 4 waves/SIMD; per-wave visits = 8..9 for EVERY wave of
// EVERY block (129 ~= 16*8): perfect balance with no scheduler luck.
// R6 LESSON (container died; ws overflow suspected): hh=0 partial o goes
// straight into `out` (f32 scratch, exactly out-sized: 512 tiles x 32x64);
// hh=1 o into a 4MB ws slab; m/l into a 256KB sidecar. New ws = +4.25MB
// (was +8.7MB). attn_merge normalizes out in place. All f32, zero precision
// change vs R5's passing kernel.
// ---------------------------------------------------------------------------
__global__ __launch_bounds__(512, 2) void attn(
    const bf16* __restrict__ Qb, const bf16* __restrict__ Kswz,
    const bf16* __restrict__ Vswz, const float* __restrict__ rel,
    float* __restrict__ out, float* __restrict__ part1, float* __restrict__ msl)
{
    __shared__ __align__(16) short sbuf[32768]; // 64 KB: 8 waves x 8 KB [K 4K|V 4K]

    const int w     = threadIdx.x >> 6;          // 0..7
    const int lane  = threadIdx.x & 63;
    const int quad  = lane >> 4;
    const int l16   = lane & 15;
    const int batch = blockIdx.x & 3;
    const int rest  = blockIdx.x >> 2;
    const int pr    = rest >> 1;                 // 0..63
    const int hh    = rest & 1;                  // KV-stream half
    const int s     = w + 8 * hh;                // this wave's stream offset 0..15

    const float SCL = 0.125f * LOG2E;
    float relreg = 0.f;
    if (lane < NRE) relreg = rel[lane] * LOG2E;
    const float rel0 = __shfl(relreg, 0, 64);

    const size_t bbase = (size_t)batch * TT;

    short* mybuf = &sbuf[w * 4096];              // 8 KB per wave
    const unsigned sbase = lds_addr(&sbuf[0]) + (unsigned)(w * 8192 + lane * 16);

    float* Osh = (float*)&sbuf[0];               // 4 slots x [32 rows][68]  ~35 KB
    float* mM  = Osh + 4 * 32 * 68;              // 256 (8 streams x 32 rows)
    float* lL  = mM + 256;

    auto stageKV = [&](int T) {
        const size_t gb = ((size_t)(batch * 512 + T * 4)) * 512;   // elems
#pragma unroll
        for (int j = 0; j < 4; j++)
            gload_lds16(&Kswz[gb + j * 512 + lane * 8], mybuf + j * 512);
#pragma unroll
        for (int j = 0; j < 4; j++)
            gload_lds16(&Vswz[gb + j * 512 + lane * 8], mybuf + 2048 + j * 512);
    };

#pragma unroll 1
    for (int ph = 0; ph < 2; ph++) {
        const int t  = ph ? (127 - pr) : pr;
        const int q0 = 32 * t;

        short8 bq[2][2];
#pragma unroll
        for (int qh = 0; qh < 2; qh++) {
            const bf16* qp = &Qb[(bbase + q0 + 16 * qh + l16) * DH];
            bq[qh][0] = load8(qp + quad * 8);
            bq[qh][1] = load8(qp + 32 + quad * 8);
        }
        __builtin_amdgcn_s_waitcnt(0xF70);   // drain Q loads

        float4v o[2][4];
#pragma unroll
        for (int qh = 0; qh < 2; qh++)
#pragma unroll
            for (int dt = 0; dt < 4; dt++) o[qh][dt] = (float4v)(0.f);
        float m_st[2] = {-1e30f, -1e30f}, l_st[2] = {0.f, 0.f};

        const int cnt = (t >= s) ? (((t - s) >> 4) + 1) : 0;
        if (cnt > 0) stageKV(s);

        for (int k = 0; k < cnt; k++) {
            const int T = s + 16 * k;
            __builtin_amdgcn_s_waitcnt(0xF70);   // vmcnt(0): tile T landed

            float4v kf0, kf1, kf2, kf3, vf0, vf1, vf2, vf3;
            DSR(kf0, sbase, "0");    DSR(kf1, sbase, "1024");
            DSR(kf2, sbase, "2048"); DSR(kf3, sbase, "3072");
            DSR(vf0, sbase, "4096"); DSR(vf1, sbase, "5120");
            DSR(vf2, sbase, "6144"); DSR(vf3, sbase, "7168");
            asm volatile("s_waitcnt lgkmcnt(0)"
                : "+v"(kf0), "+v"(kf1), "+v"(kf2), "+v"(kf3),
                  "+v"(vf0), "+v"(vf1), "+v"(vf2), "+v"(vf3));

            // buffer now dead: issue next tile's DMA; latency hides under compute
            if (k + 1 < cnt) stageKV(s + 16 * (k + 1));

            const int js = 32 * T;
#pragma unroll
            for (int qh = 0; qh < 2; qh++) {
                float4v st[2];
                st[0] = (float4v)(0.f); st[1] = (float4v)(0.f);
                __builtin_amdgcn_s_setprio(1);
                st[0] = __builtin_amdgcn_mfma_f32_16x16x32_bf16(BC8(kf0), bq[qh][0], st[0], 0, 0, 0);
                st[0] = __builtin_amdgcn_mfma_f32_16x16x32_bf16(BC8(kf1), bq[qh][1], st[0], 0, 0, 0);
                st[1] = __builtin_amdgcn_mfma_f32_16x16x32_bf16(BC8(kf2), bq[qh][0], st[1], 0, 0, 0);
                st[1] = __builtin_amdgcn_mfma_f32_16x16x32_bf16(BC8(kf3), bq[qh][1], st[1], 0, 0, 0);
                __builtin_amdgcn_s_setprio(0);

                const int i_row = q0 + 16 * qh + l16;
                float mcur = -1e30f;
                if (js + 40 <= q0 + 16 * qh) {       // interior: bias=rel0, no mask
#pragma unroll
                    for (int n = 0; n < 2; n++)
#pragma unroll
                        for (int r = 0; r < 4; r++) {
                            float v = st[n][r] * SCL + rel0;
                            st[n][r] = v;
                            mcur = fmaxf(mcur, v);
                        }
                } else {
#pragma unroll
                    for (int n = 0; n < 2; n++) {
                        const int jb = js + 16 * n + 4 * quad;
#pragma unroll
                        for (int r = 0; r < 4; r++) {
                            const int d = jb + r - i_row;
                            int idx = d + 8;
                            idx = idx < 0 ? 0 : (idx > 16 ? 16 : idx);
                            float v = st[n][r] * SCL + __shfl(relreg, idx, 64);
                            v = (d > 0) ? -1e30f : v;
                            st[n][r] = v;
                            mcur = fmaxf(mcur, v);
                        }
                    }
                }

                mcur = fmaxf(mcur, __shfl_xor(mcur, 16, 64));
                mcur = fmaxf(mcur, __shfl_xor(mcur, 32, 64));

                // T13 defer-max: only rescale when the wave's max grew > 8
                if (__any(mcur > m_st[qh] + 8.f)) {
                    const float mn = fmaxf(m_st[qh], mcur);
                    const float alpha = exp2f(m_st[qh] - mn);
                    m_st[qh] = mn;
                    l_st[qh] *= alpha;
#pragma unroll
                    for (int dt = 0; dt < 4; dt++)
#pragma unroll
                        for (int r = 0; r < 4; r++) o[qh][dt][r] *= alpha;
                }
                const float mn = m_st[qh];

                float lsum = 0.f;
                short4v pb[2];
#pragma unroll
                for (int n = 0; n < 2; n++)
#pragma unroll
                    for (int r = 0; r < 4; r++) {
                        const float e = exp2f(st[n][r] - mn);
                        lsum += e;
                        pb[n][r] = bfbits(e);
                    }
                lsum += __shfl_xor(lsum, 16, 64);
                lsum += __shfl_xor(lsum, 32, 64);
                l_st[qh] += lsum;

                __builtin_amdgcn_s_setprio(1);
#pragma unroll
                for (int n = 0; n < 2; n++) {
#pragma unroll
                    for (int dh = 0; dh < 2; dh++) {
                        const short8 vs = BC8((dh == 0) ? ((n == 0) ? vf0 : vf2)
                                                        : ((n == 0) ? vf1 : vf3));
                        short4v lo, hi;
                        lo[0] = vs[0]; lo[1] = vs[1]; lo[2] = vs[2]; lo[3] = vs[3];
                        hi[0] = vs[4]; hi[1] = vs[5]; hi[2] = vs[6]; hi[3] = vs[7];
                        o[qh][2 * dh]     = __builtin_amdgcn_mfma_f32_16x16x16bf16_1k(lo, pb[n], o[qh][2 * dh], 0, 0, 0);
                        o[qh][2 * dh + 1] = __builtin_amdgcn_mfma_f32_16x16x16bf16_1k(hi, pb[n], o[qh][2 * dh + 1], 0, 0, 0);
                    }
                }
                __builtin_amdgcn_s_setprio(0);
            }
        }

        // ---- hierarchical merge: 8 -> 4 -> partial write (all f32) ----
        __syncthreads();                          // KV loop done, sbuf free
        if (w >= 4) {                             // pass 1: high waves retire o NOW
            const int slot = w - 4;
#pragma unroll
            for (int qh = 0; qh < 2; qh++) {
                const int row = 16 * qh + l16;    // 0..31 within slot
                if (quad == 0) { mM[w * 32 + row] = m_st[qh]; lL[w * 32 + row] = l_st[qh]; }
#pragma unroll
                for (int dt = 0; dt < 4; dt++)
                    *reinterpret_cast<float4v*>(&Osh[(slot * 32 + row) * 68 + 16 * dt + 4 * quad]) = o[qh][dt];
            }
        }
        __syncthreads();
        if (w < 4) {                              // pass 2: fold partner into regs
#pragma unroll
            for (int qh = 0; qh < 2; qh++) {
                const int row = 16 * qh + l16;
                const float mp = mM[(w + 4) * 32 + row], lp = lL[(w + 4) * 32 + row];
                const float M  = fmaxf(m_st[qh], mp);
                const float ea = exp2f(m_st[qh] - M);
                const float eb = exp2f(mp - M);
                const float ln = l_st[qh] * ea + lp * eb;
#pragma unroll
                for (int dt = 0; dt < 4; dt++) {
                    float4v op = *reinterpret_cast<float4v*>(&Osh[(w * 32 + row) * 68 + 16 * dt + 4 * quad]);
#pragma unroll
                    for (int r = 0; r < 4; r++) o[qh][dt][r] = o[qh][dt][r] * ea + op[r] * eb;
                }
                if (quad == 0) { mM[w * 32 + row] = M; lL[w * 32 + row] = ln; }
#pragma unroll
                for (int dt = 0; dt < 4; dt++)
                    *reinterpret_cast<float4v*>(&Osh[(w * 32 + row) * 68 + 16 * dt + 4 * quad]) = o[qh][dt];
            }
        }
        __syncthreads();
        {   // pass 3: 4-slot merge -> UNNORMALIZED partial
            // hh=0 -> out (f32 scratch, exactly tile-sized); hh=1 -> part1.
            const int q = batch * 128 + t;
            float* ob = hh ? (part1 + (size_t)q * 2048)
                           : (out + ((size_t)bbase + q0) * DH);
            float* ml = msl + (size_t)(q * 2 + hh) * 64;
            for (int idx = threadIdx.x; idx < 32 * 64; idx += 512) {
                const int row = idx >> 6;
                const int col = idx & 63;
                float M = mM[row];
#pragma unroll
                for (int s2 = 1; s2 < 4; s2++) M = fmaxf(M, mM[s2 * 32 + row]);
                float L = 0.f, a = 0.f;
#pragma unroll
                for (int s2 = 0; s2 < 4; s2++) {
                    const float ex = exp2f(mM[s2 * 32 + row] - M);
                    L += lL[s2 * 32 + row] * ex;
                    a += Osh[(s2 * 32 + row) * 68 + col] * ex;
                }
                ob[idx] = a;
                if (col == 0) { ml[row] = M; ml[32 + row] = L; }
            }
        }
        __syncthreads();   // merge reads done before next phase's KV DMA reuses sbuf
    }
}

// ---------------------------------------------------------------------------
// Kernel 3: combine the two split-K halves per q-tile; normalizes `out`
// in place. 512 blocks x 256 thr (each thread reads both halves, writes once).
// ---------------------------------------------------------------------------
__global__ __launch_bounds__(256) void attn_merge(
    const float* __restrict__ part1, const float* __restrict__ msl,
    float* __restrict__ out)
{
    const int q = blockIdx.x;              // batch*128 + t
    const int batch = q >> 7, t = q & 127;
    float* ob0 = out + ((size_t)batch * TT + t * 32) * DH;
    const float* o1  = part1 + (size_t)q * 2048;
    const float* ml0 = msl + (size_t)(q * 2 + 0) * 64;
    const float* ml1 = msl + (size_t)(q * 2 + 1) * 64;
    for (int idx = threadIdx.x; idx < 32 * 64; idx += 256) {
        const int row = idx >> 6;
        const float m0 = ml0[row], m1 = ml1[row];
        const float l0 = ml0[32 + row], l1 = ml1[32 + row];
        const float M  = fmaxf(m0, m1);
        const float e0 = exp2f(m0 - M), e1 = exp2f(m1 - M);
        const float den = l0 * e0 + l1 * e1;
        const float num = ob0[idx] * e0 + o1[idx] * e1;
        ob0[idx] = num / den;
    }
}

// ---------------------------------------------------------------------------
extern "C" void kernel_launch(void* const* d_in, const int* in_sizes, int n_in,
                              void* d_out, int out_size, void* d_ws, size_t ws_size,
                              hipStream_t stream)
{
    const float* x   = (const float*)d_in[0];
    const float* Wq  = (const float*)d_in[1];
    const float* Wk  = (const float*)d_in[2];
    const float* Wv  = (const float*)d_in[3];
    const float* rel = (const float*)d_in[4];
    float* out = (float*)d_out;

    bf16* Qb   = (bf16*)d_ws;                         // [B*T,64]        2 MB
    bf16* Kswz = Qb   + (size_t)BT * TT * DH;         // frag-ordered    2 MB
    bf16* Vswz = Kswz + (size_t)BT * TT * DH;         // frag-ordered    2 MB
    bf16* Wswz = Vswz + (size_t)BT * TT * DH;         // swizzled W    384 KB
    float* part1 = (float*)(Wswz + 24576 * 8);        // 512 x 2048 f32   4 MB
    float* msl   = part1 + (size_t)512 * 2048;        // 1024 x 64 f32  256 KB

    w_prep<<<96, 256, 0, stream>>>(Wq, Wk, Wv, Wswz);
    qkv_gemm<<<512, 256, 0, stream>>>(x, Wswz, Qb, Kswz, Vswz);
    attn<<<512, 512, 0, stream>>>(Qb, Kswz, Vswz, rel, out, part1, msl);
    attn_merge<<<512, 256, 0, stream>>>(part1, msl, out);
}

// Round 8
// 156.085 us; speedup vs baseline: 1.0447x; 1.0447x over previous
//
#include <hip/hip_runtime.h>
#include <hip/hip_bf16.h>

#define BT 4
#define TT 4096
#define DM 1024
#define DH 64
#define NRE 17
#define LOG2E 1.4426950408889634f

using bf16 = __hip_bfloat16;
typedef __attribute__((ext_vector_type(8))) short short8;
typedef __attribute__((ext_vector_type(4))) short short4v;
typedef __attribute__((ext_vector_type(4))) float float4v;

#define BC8(x) __builtin_bit_cast(short8, x)

static __device__ __forceinline__ short8 load8(const bf16* p) {
    return *reinterpret_cast<const short8*>(p);
}
static __device__ __forceinline__ short bfbits(float x) {
    return (short)__bfloat16_as_ushort(__float2bfloat16(x));
}
static __device__ __forceinline__ short8 pack8(float4v a, float4v b) {
    short8 r;
    r[0] = bfbits(a[0]); r[1] = bfbits(a[1]); r[2] = bfbits(a[2]); r[3] = bfbits(a[3]);
    r[4] = bfbits(b[0]); r[5] = bfbits(b[1]); r[6] = bfbits(b[2]); r[7] = bfbits(b[3]);
    return r;
}
static __device__ __forceinline__ void gload_lds16(const void* g, void* l) {
    __builtin_amdgcn_global_load_lds(
        (const __attribute__((address_space(1))) void*)g,
        (__attribute__((address_space(3))) void*)l, 16, 0, 0);
}
static __device__ __forceinline__ unsigned lds_addr(const void* p) {
    return (unsigned)(size_t)(const __attribute__((address_space(3))) void*)p;
}

// invisible-to-waitcnt-pass LDS fragment read (offset must be a literal string)
#define DSR(dst, addr, off) \
    asm volatile("ds_read_b128 %0, %1 offset:" off : "=v"(dst) : "v"(addr))

// ===========================================================================
// Swizzled global layouts (16B units, frag-major) — identical to prior rounds.
// ===========================================================================

__global__ __launch_bounds__(256) void w_prep(
    const float* __restrict__ Wq, const float* __restrict__ Wk,
    const float* __restrict__ Wv, bf16* __restrict__ Wswz)
{
    const unsigned g = blockIdx.x * 256 + threadIdx.x;   // < 24576
    const unsigned c    = g / 768;
    const unsigned rem  = g - c * 768;
    const unsigned pair = rem >> 3;
    const unsigned slot = rem & 7;
    const unsigned l    = slot ^ (pair & 7);
    const unsigned row  = 2 * pair + (l >> 2);
    const unsigned k    = 32 * c + (l & 3) * 8;
    const float* src = (row < 64) ? &Wq[(size_t)row * DM + k]
                     : (row < 128) ? &Wk[(size_t)(row - 64) * DM + k]
                                   : &Wv[(size_t)(row - 128) * DM + k];
    float4v a = *reinterpret_cast<const float4v*>(src);
    float4v b = *reinterpret_cast<const float4v*>(src + 4);
    *reinterpret_cast<short8*>(&Wswz[(size_t)g * 8]) = pack8(a, b);
}

// ---------------------------------------------------------------------------
// Kernel 1: QKV GEMM. Unchanged (proven; not current bottleneck).
// ---------------------------------------------------------------------------
__global__ __launch_bounds__(256, 2) void qkv_gemm(
    const float* __restrict__ x, const bf16* __restrict__ Wswz,
    bf16* __restrict__ Qb, bf16* __restrict__ Kswz, bf16* __restrict__ Vswz)
{
    __shared__ __align__(16) float xs[2][2048];   // 2 x 8 KB  [row(32)][unit(16)]
    __shared__ __align__(16) short Wls[2][12288]; // 2 x 24 KB (2 swz chunks)

    const int w    = threadIdx.x >> 6;
    const int lane = threadIdx.x & 63;
    const int quad = lane >> 4;
    const int l16  = lane & 15;
    const int half = w & 1;
    const int colh = w >> 1;
    const int row0 = blockIdx.x * 32;

    float4v acc[6];
#pragma unroll
    for (int i = 0; i < 6; i++) acc[i] = (float4v)(0.f);

    auto stage = [&](int c, int p) {
#pragma unroll
        for (int j = 0; j < 2; j++) {
            const int call = 2 * w + j;
            const int row  = 4 * call + (lane >> 4);
            const int pu   = lane & 15;
            const int gu   = (pu & 8) | ((pu ^ row) & 7);
            gload_lds16(&x[(size_t)(row0 + row) * DM + c * 64 + gu * 4],
                        &xs[p][call * 256]);
        }
#pragma unroll
        for (int j = 0; j < 6; j++) {
            const int call = 6 * w + j;
            gload_lds16(&Wswz[(size_t)(2 * c) * 6144 + call * 512 + lane * 8],
                        &Wls[p][call * 512]);
        }
    };

    const unsigned xlds = lds_addr(&xs[0][0]);
    const unsigned wlds = lds_addr(&Wls[0][0]);
    const int R        = 16 * half + l16;
    const int lo3_0    = (2 * quad)     ^ (R & 7);
    const int lo3_1    = (2 * quad + 1) ^ (R & 7);
    const int pairBase = 48 * colh + (l16 >> 1);
    const int physW    = ((l16 & 1) * 4 + quad) ^ ((l16 >> 1) & 7);

    stage(0, 0);

    for (int c = 0; c < 16; c++) {
        const int p = c & 1;
        __syncthreads();
        if (c + 1 < 16) stage(c + 1, p ^ 1);

        const unsigned xb  = xlds + (unsigned)(p * 8192) + R * 64 * 4;
        const unsigned xa0 = xb + lo3_0 * 16;
        const unsigned xa1 = xb + lo3_1 * 16;
        const unsigned wa  = wlds + (unsigned)(p * 24576) + pairBase * 128 + physW * 16;

        float4v x00, x01, x10, x11;
        float4v w00, w01, w02, w03, w04, w05, w10, w11, w12, w13, w14, w15;
        DSR(x00, xa0, "0");   DSR(x10, xa0, "128");
        DSR(x01, xa1, "0");   DSR(x11, xa1, "128");
        DSR(w00, wa, "0");     DSR(w01, wa, "1024");  DSR(w02, wa, "2048");
        DSR(w03, wa, "3072");  DSR(w04, wa, "4096");  DSR(w05, wa, "5120");
        DSR(w10, wa, "12288"); DSR(w11, wa, "13312"); DSR(w12, wa, "14336");
        DSR(w13, wa, "15360"); DSR(w14, wa, "16384"); DSR(w15, wa, "17408");
        asm volatile("s_waitcnt lgkmcnt(0)"
            : "+v"(x00), "+v"(x01), "+v"(x10), "+v"(x11),
              "+v"(w00), "+v"(w01), "+v"(w02), "+v"(w03), "+v"(w04), "+v"(w05),
              "+v"(w10), "+v"(w11), "+v"(w12), "+v"(w13), "+v"(w14), "+v"(w15));

        short8 a0 = pack8(x00, x01);
        short8 a1 = pack8(x10, x11);
        acc[0] = __builtin_amdgcn_mfma_f32_16x16x32_bf16(a0, BC8(w00), acc[0], 0, 0, 0);
        acc[1] = __builtin_amdgcn_mfma_f32_16x16x32_bf16(a0, BC8(w01), acc[1], 0, 0, 0);
        acc[2] = __builtin_amdgcn_mfma_f32_16x16x32_bf16(a0, BC8(w02), acc[2], 0, 0, 0);
        acc[3] = __builtin_amdgcn_mfma_f32_16x16x32_bf16(a0, BC8(w03), acc[3], 0, 0, 0);
        acc[4] = __builtin_amdgcn_mfma_f32_16x16x32_bf16(a0, BC8(w04), acc[4], 0, 0, 0);
        acc[5] = __builtin_amdgcn_mfma_f32_16x16x32_bf16(a0, BC8(w05), acc[5], 0, 0, 0);
        acc[0] = __builtin_amdgcn_mfma_f32_16x16x32_bf16(a1, BC8(w10), acc[0], 0, 0, 0);
        acc[1] = __builtin_amdgcn_mfma_f32_16x16x32_bf16(a1, BC8(w11), acc[1], 0, 0, 0);
        acc[2] = __builtin_amdgcn_mfma_f32_16x16x32_bf16(a1, BC8(w12), acc[2], 0, 0, 0);
        acc[3] = __builtin_amdgcn_mfma_f32_16x16x32_bf16(a1, BC8(w13), acc[3], 0, 0, 0);
        acc[4] = __builtin_amdgcn_mfma_f32_16x16x32_bf16(a1, BC8(w14), acc[4], 0, 0, 0);
        acc[5] = __builtin_amdgcn_mfma_f32_16x16x32_bf16(a1, BC8(w15), acc[5], 0, 0, 0);
    }

    // ---- epilogue: Q direct; K/V through LDS images (alias xs) ----
    __syncthreads();
    short* Kimg = (short*)&xs[0][0];      // 4 KB (256 units)
    short* Vimg = Kimg + 2048;            // 4 KB
#pragma unroll
    for (int nt = 0; nt < 6; nt++) {
        const int cc = 96 * colh + 16 * nt + l16;          // 0..191
#pragma unroll
        for (int r = 0; r < 4; r++) {
            const int jl = 16 * half + 4 * quad + r;       // local row 0..31
            const short hb = bfbits(acc[nt][r]);
            if (cc < 64) {
                Qb[(size_t)(row0 + jl) * DH + cc] = __hip_bfloat16_raw{(unsigned short)hb};
            } else if (cc < 128) {
                const int k  = cc - 64;
                const int h  = k >> 5;
                const int q2 = (k & 31) >> 3;
                Kimg[((2 * half + h) * 64 + q2 * 16 + 4 * quad + r) * 8 + (k & 7)] = hb;
            } else {
                const int d  = cc - 128;
                const int dh = d >> 5;
                const int hi = (d >> 4) & 1;
                Vimg[((2 * half + dh) * 64 + quad * 16 + (d & 15)) * 8 + hi * 4 + r] = hb;
            }
        }
    }
    __syncthreads();
    {
        const int b_     = row0 >> 12;
        const int tile32 = (row0 & (TT - 1)) >> 5;
        const size_t base = ((size_t)(b_ * 512 + tile32 * 4)) * 512;  // elems
        const int u = threadIdx.x;                                    // 256 units
        *reinterpret_cast<short8*>(&Kswz[base + (size_t)u * 8]) =
            *reinterpret_cast<const short8*>(&Kimg[u * 8]);
        *reinterpret_cast<short8*>(&Vswz[base + (size_t)u * 8]) =
            *reinterpret_cast<const short8*>(&Vimg[u * 8]);
    }
}

// ---------------------------------------------------------------------------
// Kernel 2: flash causal attention — SPLIT-K pair blocks, register-direct KV.
// Grid = 4 batch x 64 pr x 2 halves = 512 blocks x 512 thr.
// R7 LESSON: with 64KB LDS/block the 2nd block never co-resided (Occupancy
// 18.9 == R1's 1-block value) -> split-K blocks serialized -> +10us. The KV
// LDS staging was a per-lane identity pass-through (each lane DMAs 16B and
// reads back exactly those bytes), so LDS added nothing but latency
// (DMA->LDS->ds_read->lgkmcnt). FIX: load K/V straight into registers
// (8 x short8 global loads per tile, same addresses/bytes). LDS drops to a
// 36KB merge area -> 2 blocks/CU can co-reside -> 4 waves/SIMD, AND the
// per-visit chain loses the LDS round-trip. K reloads after its last use
// (qh1 QK^T), V after its last use (qh1 PV): 1-deep prefetch hidden under
// adjacent-tile compute; compiler auto-inserts counted vmcnt for reg loads.
// Merge + split (proven correct in R7) unchanged: hh=0 partial into `out`,
// hh=1 into part1, m/l sidecar; attn_merge normalizes in place.
// ---------------------------------------------------------------------------
__global__ __launch_bounds__(512, 2) void attn(
    const bf16* __restrict__ Qb, const bf16* __restrict__ Kswz,
    const bf16* __restrict__ Vswz, const float* __restrict__ rel,
    float* __restrict__ out, float* __restrict__ part1, float* __restrict__ msl)
{
    __shared__ __align__(16) float smem[9216];   // 36 KB: Osh 4x32x68 + mM/lL

    const int w     = threadIdx.x >> 6;          // 0..7
    const int lane  = threadIdx.x & 63;
    const int quad  = lane >> 4;
    const int l16   = lane & 15;
    const int batch = blockIdx.x & 3;
    const int rest  = blockIdx.x >> 2;
    const int pr    = rest >> 1;                 // 0..63
    const int hh    = rest & 1;                  // KV-stream half
    const int s     = w + 8 * hh;                // this wave's stream offset 0..15

    const float SCL = 0.125f * LOG2E;
    float relreg = 0.f;
    if (lane < NRE) relreg = rel[lane] * LOG2E;
    const float rel0 = __shfl(relreg, 0, 64);

    const size_t bbase = (size_t)batch * TT;

    float* Osh = smem;                           // 4 slots x [32 rows][68]
    float* mM  = Osh + 4 * 32 * 68;              // 256 (8 streams x 32 rows)
    float* lL  = mM + 256;

    const unsigned loff = (unsigned)lane * 8;    // elems within 512-elem unit row

#pragma unroll 1
    for (int ph = 0; ph < 2; ph++) {
        const int t  = ph ? (127 - pr) : pr;
        const int q0 = 32 * t;

        short8 bq[2][2];
#pragma unroll
        for (int qh = 0; qh < 2; qh++) {
            const bf16* qp = &Qb[(bbase + q0 + 16 * qh + l16) * DH];
            bq[qh][0] = load8(qp + quad * 8);
            bq[qh][1] = load8(qp + 32 + quad * 8);
        }

        float4v o[2][4];
#pragma unroll
        for (int qh = 0; qh < 2; qh++)
#pragma unroll
            for (int dt = 0; dt < 4; dt++) o[qh][dt] = (float4v)(0.f);
        float m_st[2] = {-1e30f, -1e30f}, l_st[2] = {0.f, 0.f};

        const int cnt = (t >= s) ? (((t - s) >> 4) + 1) : 0;

        short8 K0, K1, K2, K3, V0, V1, V2, V3;
        if (cnt > 0) {
            const bf16* kp = Kswz + ((size_t)(batch * 512 + s * 4)) * 512 + loff;
            const bf16* vp = Vswz + ((size_t)(batch * 512 + s * 4)) * 512 + loff;
            K0 = load8(kp);        K1 = load8(kp + 512);
            K2 = load8(kp + 1024); K3 = load8(kp + 1536);
            V0 = load8(vp);        V1 = load8(vp + 512);
            V2 = load8(vp + 1024); V3 = load8(vp + 1536);
        }

        for (int k = 0; k < cnt; k++) {
            const int T  = s + 16 * k;
            const int js = 32 * T;
#pragma unroll
            for (int qh = 0; qh < 2; qh++) {
                float4v st[2];
                st[0] = (float4v)(0.f); st[1] = (float4v)(0.f);
                __builtin_amdgcn_s_setprio(1);
                st[0] = __builtin_amdgcn_mfma_f32_16x16x32_bf16(K0, bq[qh][0], st[0], 0, 0, 0);
                st[0] = __builtin_amdgcn_mfma_f32_16x16x32_bf16(K1, bq[qh][1], st[0], 0, 0, 0);
                st[1] = __builtin_amdgcn_mfma_f32_16x16x32_bf16(K2, bq[qh][0], st[1], 0, 0, 0);
                st[1] = __builtin_amdgcn_mfma_f32_16x16x32_bf16(K3, bq[qh][1], st[1], 0, 0, 0);
                __builtin_amdgcn_s_setprio(0);

                // K consumed for this tile after qh==1: prefetch next tile's K
                if (qh == 1 && k + 1 < cnt) {
                    const bf16* kp = Kswz + ((size_t)(batch * 512 + (T + 16) * 4)) * 512 + loff;
                    K0 = load8(kp);        K1 = load8(kp + 512);
                    K2 = load8(kp + 1024); K3 = load8(kp + 1536);
                }

                const int i_row = q0 + 16 * qh + l16;
                float mcur = -1e30f;
                if (js + 40 <= q0 + 16 * qh) {       // interior: bias=rel0, no mask
#pragma unroll
                    for (int n = 0; n < 2; n++)
#pragma unroll
                        for (int r = 0; r < 4; r++) {
                            float v = st[n][r] * SCL + rel0;
                            st[n][r] = v;
                            mcur = fmaxf(mcur, v);
                        }
                } else {
#pragma unroll
                    for (int n = 0; n < 2; n++) {
                        const int jb = js + 16 * n + 4 * quad;
#pragma unroll
                        for (int r = 0; r < 4; r++) {
                            const int d = jb + r - i_row;
                            int idx = d + 8;
                            idx = idx < 0 ? 0 : (idx > 16 ? 16 : idx);
                            float v = st[n][r] * SCL + __shfl(relreg, idx, 64);
                            v = (d > 0) ? -1e30f : v;
                            st[n][r] = v;
                            mcur = fmaxf(mcur, v);
                        }
                    }
                }

                mcur = fmaxf(mcur, __shfl_xor(mcur, 16, 64));
                mcur = fmaxf(mcur, __shfl_xor(mcur, 32, 64));

                // T13 defer-max: only rescale when the wave's max grew > 8
                if (__any(mcur > m_st[qh] + 8.f)) {
                    const float mn = fmaxf(m_st[qh], mcur);
                    const float alpha = exp2f(m_st[qh] - mn);
                    m_st[qh] = mn;
                    l_st[qh] *= alpha;
#pragma unroll
                    for (int dt = 0; dt < 4; dt++)
#pragma unroll
                        for (int r = 0; r < 4; r++) o[qh][dt][r] *= alpha;
                }
                const float mn = m_st[qh];

                float lsum = 0.f;
                short4v pb[2];
#pragma unroll
                for (int n = 0; n < 2; n++)
#pragma unroll
                    for (int r = 0; r < 4; r++) {
                        const float e = exp2f(st[n][r] - mn);
                        lsum += e;
                        pb[n][r] = bfbits(e);
                    }
                lsum += __shfl_xor(lsum, 16, 64);
                lsum += __shfl_xor(lsum, 32, 64);
                l_st[qh] += lsum;

                __builtin_amdgcn_s_setprio(1);
#pragma unroll
                for (int n = 0; n < 2; n++) {
#pragma unroll
                    for (int dh = 0; dh < 2; dh++) {
                        const short8 vs = (dh == 0) ? ((n == 0) ? V0 : V2)
                                                    : ((n == 0) ? V1 : V3);
                        short4v lo, hi;
                        lo[0] = vs[0]; lo[1] = vs[1]; lo[2] = vs[2]; lo[3] = vs[3];
                        hi[0] = vs[4]; hi[1] = vs[5]; hi[2] = vs[6]; hi[3] = vs[7];
                        o[qh][2 * dh]     = __builtin_amdgcn_mfma_f32_16x16x16bf16_1k(lo, pb[n], o[qh][2 * dh], 0, 0, 0);
                        o[qh][2 * dh + 1] = __builtin_amdgcn_mfma_f32_16x16x16bf16_1k(hi, pb[n], o[qh][2 * dh + 1], 0, 0, 0);
                    }
                }
                __builtin_amdgcn_s_setprio(0);

                // V consumed for this tile after qh==1: prefetch next tile's V
                if (qh == 1 && k + 1 < cnt) {
                    const bf16* vp = Vswz + ((size_t)(batch * 512 + (T + 16) * 4)) * 512 + loff;
                    V0 = load8(vp);        V1 = load8(vp + 512);
                    V2 = load8(vp + 1024); V3 = load8(vp + 1536);
                }
            }
        }

        // ---- hierarchical merge: 8 -> 4 -> partial write (all f32) ----
        __syncthreads();                          // prior phase's merge reads done
        if (w >= 4) {                             // pass 1: high waves retire o NOW
            const int slot = w - 4;
#pragma unroll
            for (int qh = 0; qh < 2; qh++) {
                const int row = 16 * qh + l16;    // 0..31 within slot
                if (quad == 0) { mM[w * 32 + row] = m_st[qh]; lL[w * 32 + row] = l_st[qh]; }
#pragma unroll
                for (int dt = 0; dt < 4; dt++)
                    *reinterpret_cast<float4v*>(&Osh[(slot * 32 + row) * 68 + 16 * dt + 4 * quad]) = o[qh][dt];
            }
        }
        __syncthreads();
        if (w < 4) {                              // pass 2: fold partner into regs
#pragma unroll
            for (int qh = 0; qh < 2; qh++) {
                const int row = 16 * qh + l16;
                const float mp = mM[(w + 4) * 32 + row], lp = lL[(w + 4) * 32 + row];
                const float M  = fmaxf(m_st[qh], mp);
                const float ea = exp2f(m_st[qh] - M);
                const float eb = exp2f(mp - M);
                const float ln = l_st[qh] * ea + lp * eb;
#pragma unroll
                for (int dt = 0; dt < 4; dt++) {
                    float4v op = *reinterpret_cast<float4v*>(&Osh[(w * 32 + row) * 68 + 16 * dt + 4 * quad]);
#pragma unroll
                    for (int r = 0; r < 4; r++) o[qh][dt][r] = o[qh][dt][r] * ea + op[r] * eb;
                }
                if (quad == 0) { mM[w * 32 + row] = M; lL[w * 32 + row] = ln; }
#pragma unroll
                for (int dt = 0; dt < 4; dt++)
                    *reinterpret_cast<float4v*>(&Osh[(w * 32 + row) * 68 + 16 * dt + 4 * quad]) = o[qh][dt];
            }
        }
        __syncthreads();
        {   // pass 3: 4-slot merge -> UNNORMALIZED partial
            // hh=0 -> out (f32 scratch, exactly tile-sized); hh=1 -> part1.
            const int q = batch * 128 + t;
            float* ob = hh ? (part1 + (size_t)q * 2048)
                           : (out + ((size_t)bbase + q0) * DH);
            float* ml = msl + (size_t)(q * 2 + hh) * 64;
            for (int idx = threadIdx.x; idx < 32 * 64; idx += 512) {
                const int row = idx >> 6;
                const int col = idx & 63;
                float M = mM[row];
#pragma unroll
                for (int s2 = 1; s2 < 4; s2++) M = fmaxf(M, mM[s2 * 32 + row]);
                float L = 0.f, a = 0.f;
#pragma unroll
                for (int s2 = 0; s2 < 4; s2++) {
                    const float ex = exp2f(mM[s2 * 32 + row] - M);
                    L += lL[s2 * 32 + row] * ex;
                    a += Osh[(s2 * 32 + row) * 68 + col] * ex;
                }
                ob[idx] = a;
                if (col == 0) { ml[row] = M; ml[32 + row] = L; }
            }
        }
        __syncthreads();   // merge reads done before next phase reuses smem
    }
}

// ---------------------------------------------------------------------------
// Kernel 3: combine the two split-K halves per q-tile; normalizes `out`
// in place. 512 blocks x 256 thr.
// ---------------------------------------------------------------------------
__global__ __launch_bounds__(256) void attn_merge(
    const float* __restrict__ part1, const float* __restrict__ msl,
    float* __restrict__ out)
{
    const int q = blockIdx.x;              // batch*128 + t
    const int batch = q >> 7, t = q & 127;
    float* ob0 = out + ((size_t)batch * TT + t * 32) * DH;
    const float* o1  = part1 + (size_t)q * 2048;
    const float* ml0 = msl + (size_t)(q * 2 + 0) * 64;
    const float* ml1 = msl + (size_t)(q * 2 + 1) * 64;
    for (int idx = threadIdx.x; idx < 32 * 64; idx += 256) {
        const int row = idx >> 6;
        const float m0 = ml0[row], m1 = ml1[row];
        const float l0 = ml0[32 + row], l1 = ml1[32 + row];
        const float M  = fmaxf(m0, m1);
        const float e0 = exp2f(m0 - M), e1 = exp2f(m1 - M);
        const float den = l0 * e0 + l1 * e1;
        const float num = ob0[idx] * e0 + o1[idx] * e1;
        ob0[idx] = num / den;
    }
}

// ---------------------------------------------------------------------------
extern "C" void kernel_launch(void* const* d_in, const int* in_sizes, int n_in,
                              void* d_out, int out_size, void* d_ws, size_t ws_size,
                              hipStream_t stream)
{
    const float* x   = (const float*)d_in[0];
    const float* Wq  = (const float*)d_in[1];
    const float* Wk  = (const float*)d_in[2];
    const float* Wv  = (const float*)d_in[3];
    const float* rel = (const float*)d_in[4];
    float* out = (float*)d_out;

    bf16* Qb   = (bf16*)d_ws;                         // [B*T,64]        2 MB
    bf16* Kswz = Qb   + (size_t)BT * TT * DH;         // frag-ordered    2 MB
    bf16* Vswz = Kswz + (size_t)BT * TT * DH;         // frag-ordered    2 MB
    bf16* Wswz = Vswz + (size_t)BT * TT * DH;         // swizzled W    384 KB
    float* part1 = (float*)(Wswz + 24576 * 8);        // 512 x 2048 f32   4 MB
    float* msl   = part1 + (size_t)512 * 2048;        // 1024 x 64 f32  256 KB

    w_prep<<<96, 256, 0, stream>>>(Wq, Wk, Wv, Wswz);
    qkv_gemm<<<512, 256, 0, stream>>>(x, Wswz, Qb, Kswz, Vswz);
    attn<<<512, 512, 0, stream>>>(Qb, Kswz, Vswz, rel, out, part1, msl);
    attn_merge<<<512, 256, 0, stream>>>(part1, msl, out);
}

// Round 9
// 144.272 us; speedup vs baseline: 1.1303x; 1.0819x over previous
//
#include <hip/hip_runtime.h>
#include <hip/hip_bf16.h>

#define BT 4
#define TT 4096
#define DM 1024
#define DH 64
#define NRE 17
#define LOG2E 1.4426950408889634f

using bf16 = __hip_bfloat16;
typedef __attribute__((ext_vector_type(8))) short short8;
typedef __attribute__((ext_vector_type(4))) short short4v;
typedef __attribute__((ext_vector_type(4))) float float4v;

#define BC8(x) __builtin_bit_cast(short8, x)

static __device__ __forceinline__ short8 load8(const bf16* p) {
    return *reinterpret_cast<const short8*>(p);
}
static __device__ __forceinline__ short bfbits(float x) {
    return (short)__bfloat16_as_ushort(__float2bfloat16(x));
}
static __device__ __forceinline__ short8 pack8(float4v a, float4v b) {
    short8 r;
    r[0] = bfbits(a[0]); r[1] = bfbits(a[1]); r[2] = bfbits(a[2]); r[3] = bfbits(a[3]);
    r[4] = bfbits(b[0]); r[5] = bfbits(b[1]); r[6] = bfbits(b[2]); r[7] = bfbits(b[3]);
    return r;
}
static __device__ __forceinline__ void gload_lds16(const void* g, void* l) {
    __builtin_amdgcn_global_load_lds(
        (const __attribute__((address_space(1))) void*)g,
        (__attribute__((address_space(3))) void*)l, 16, 0, 0);
}
static __device__ __forceinline__ unsigned lds_addr(const void* p) {
    return (unsigned)(size_t)(const __attribute__((address_space(3))) void*)p;
}

// invisible-to-waitcnt-pass LDS fragment read (offset must be a literal string)
#define DSR(dst, addr, off) \
    asm volatile("ds_read_b128 %0, %1 offset:" off : "=v"(dst) : "v"(addr))

// ===========================================================================
// Swizzled global layouts (16B units, frag-major) — identical to prior rounds.
// ===========================================================================

__global__ __launch_bounds__(256) void w_prep(
    const float* __restrict__ Wq, const float* __restrict__ Wk,
    const float* __restrict__ Wv, bf16* __restrict__ Wswz)
{
    const unsigned g = blockIdx.x * 256 + threadIdx.x;   // < 24576
    const unsigned c    = g / 768;
    const unsigned rem  = g - c * 768;
    const unsigned pair = rem >> 3;
    const unsigned slot = rem & 7;
    const unsigned l    = slot ^ (pair & 7);
    const unsigned row  = 2 * pair + (l >> 2);
    const unsigned k    = 32 * c + (l & 3) * 8;
    const float* src = (row < 64) ? &Wq[(size_t)row * DM + k]
                     : (row < 128) ? &Wk[(size_t)(row - 64) * DM + k]
                                   : &Wv[(size_t)(row - 128) * DM + k];
    float4v a = *reinterpret_cast<const float4v*>(src);
    float4v b = *reinterpret_cast<const float4v*>(src + 4);
    *reinterpret_cast<short8*>(&Wswz[(size_t)g * 8]) = pack8(a, b);
}

// ---------------------------------------------------------------------------
// Kernel 1: QKV GEMM. Unchanged (proven; not current bottleneck).
// ---------------------------------------------------------------------------
__global__ __launch_bounds__(256, 2) void qkv_gemm(
    const float* __restrict__ x, const bf16* __restrict__ Wswz,
    bf16* __restrict__ Qb, bf16* __restrict__ Kswz, bf16* __restrict__ Vswz)
{
    __shared__ __align__(16) float xs[2][2048];   // 2 x 8 KB  [row(32)][unit(16)]
    __shared__ __align__(16) short Wls[2][12288]; // 2 x 24 KB (2 swz chunks)

    const int w    = threadIdx.x >> 6;
    const int lane = threadIdx.x & 63;
    const int quad = lane >> 4;
    const int l16  = lane & 15;
    const int half = w & 1;
    const int colh = w >> 1;
    const int row0 = blockIdx.x * 32;

    float4v acc[6];
#pragma unroll
    for (int i = 0; i < 6; i++) acc[i] = (float4v)(0.f);

    auto stage = [&](int c, int p) {
#pragma unroll
        for (int j = 0; j < 2; j++) {
            const int call = 2 * w + j;
            const int row  = 4 * call + (lane >> 4);
            const int pu   = lane & 15;
            const int gu   = (pu & 8) | ((pu ^ row) & 7);
            gload_lds16(&x[(size_t)(row0 + row) * DM + c * 64 + gu * 4],
                        &xs[p][call * 256]);
        }
#pragma unroll
        for (int j = 0; j < 6; j++) {
            const int call = 6 * w + j;
            gload_lds16(&Wswz[(size_t)(2 * c) * 6144 + call * 512 + lane * 8],
                        &Wls[p][call * 512]);
        }
    };

    const unsigned xlds = lds_addr(&xs[0][0]);
    const unsigned wlds = lds_addr(&Wls[0][0]);
    const int R        = 16 * half + l16;
    const int lo3_0    = (2 * quad)     ^ (R & 7);
    const int lo3_1    = (2 * quad + 1) ^ (R & 7);
    const int pairBase = 48 * colh + (l16 >> 1);
    const int physW    = ((l16 & 1) * 4 + quad) ^ ((l16 >> 1) & 7);

    stage(0, 0);

    for (int c = 0; c < 16; c++) {
        const int p = c & 1;
        __syncthreads();
        if (c + 1 < 16) stage(c + 1, p ^ 1);

        const unsigned xb  = xlds + (unsigned)(p * 8192) + R * 64 * 4;
        const unsigned xa0 = xb + lo3_0 * 16;
        const unsigned xa1 = xb + lo3_1 * 16;
        const unsigned wa  = wlds + (unsigned)(p * 24576) + pairBase * 128 + physW * 16;

        float4v x00, x01, x10, x11;
        float4v w00, w01, w02, w03, w04, w05, w10, w11, w12, w13, w14, w15;
        DSR(x00, xa0, "0");   DSR(x10, xa0, "128");
        DSR(x01, xa1, "0");   DSR(x11, xa1, "128");
        DSR(w00, wa, "0");     DSR(w01, wa, "1024");  DSR(w02, wa, "2048");
        DSR(w03, wa, "3072");  DSR(w04, wa, "4096");  DSR(w05, wa, "5120");
        DSR(w10, wa, "12288"); DSR(w11, wa, "13312"); DSR(w12, wa, "14336");
        DSR(w13, wa, "15360"); DSR(w14, wa, "16384"); DSR(w15, wa, "17408");
        asm volatile("s_waitcnt lgkmcnt(0)"
            : "+v"(x00), "+v"(x01), "+v"(x10), "+v"(x11),
              "+v"(w00), "+v"(w01), "+v"(w02), "+v"(w03), "+v"(w04), "+v"(w05),
              "+v"(w10), "+v"(w11), "+v"(w12), "+v"(w13), "+v"(w14), "+v"(w15));

        short8 a0 = pack8(x00, x01);
        short8 a1 = pack8(x10, x11);
        acc[0] = __builtin_amdgcn_mfma_f32_16x16x32_bf16(a0, BC8(w00), acc[0], 0, 0, 0);
        acc[1] = __builtin_amdgcn_mfma_f32_16x16x32_bf16(a0, BC8(w01), acc[1], 0, 0, 0);
        acc[2] = __builtin_amdgcn_mfma_f32_16x16x32_bf16(a0, BC8(w02), acc[2], 0, 0, 0);
        acc[3] = __builtin_amdgcn_mfma_f32_16x16x32_bf16(a0, BC8(w03), acc[3], 0, 0, 0);
        acc[4] = __builtin_amdgcn_mfma_f32_16x16x32_bf16(a0, BC8(w04), acc[4], 0, 0, 0);
        acc[5] = __builtin_amdgcn_mfma_f32_16x16x32_bf16(a0, BC8(w05), acc[5], 0, 0, 0);
        acc[0] = __builtin_amdgcn_mfma_f32_16x16x32_bf16(a1, BC8(w10), acc[0], 0, 0, 0);
        acc[1] = __builtin_amdgcn_mfma_f32_16x16x32_bf16(a1, BC8(w11), acc[1], 0, 0, 0);
        acc[2] = __builtin_amdgcn_mfma_f32_16x16x32_bf16(a1, BC8(w12), acc[2], 0, 0, 0);
        acc[3] = __builtin_amdgcn_mfma_f32_16x16x32_bf16(a1, BC8(w13), acc[3], 0, 0, 0);
        acc[4] = __builtin_amdgcn_mfma_f32_16x16x32_bf16(a1, BC8(w14), acc[4], 0, 0, 0);
        acc[5] = __builtin_amdgcn_mfma_f32_16x16x32_bf16(a1, BC8(w15), acc[5], 0, 0, 0);
    }

    // ---- epilogue: Q direct; K/V through LDS images (alias xs) ----
    __syncthreads();
    short* Kimg = (short*)&xs[0][0];      // 4 KB (256 units)
    short* Vimg = Kimg + 2048;            // 4 KB
#pragma unroll
    for (int nt = 0; nt < 6; nt++) {
        const int cc = 96 * colh + 16 * nt + l16;          // 0..191
#pragma unroll
        for (int r = 0; r < 4; r++) {
            const int jl = 16 * half + 4 * quad + r;       // local row 0..31
            const short hb = bfbits(acc[nt][r]);
            if (cc < 64) {
                Qb[(size_t)(row0 + jl) * DH + cc] = __hip_bfloat16_raw{(unsigned short)hb};
            } else if (cc < 128) {
                const int k  = cc - 64;
                const int h  = k >> 5;
                const int q2 = (k & 31) >> 3;
                Kimg[((2 * half + h) * 64 + q2 * 16 + 4 * quad + r) * 8 + (k & 7)] = hb;
            } else {
                const int d  = cc - 128;
                const int dh = d >> 5;
                const int hi = (d >> 4) & 1;
                Vimg[((2 * half + dh) * 64 + quad * 16 + (d & 15)) * 8 + hi * 4 + r] = hb;
            }
        }
    }
    __syncthreads();
    {
        const int b_     = row0 >> 12;
        const int tile32 = (row0 & (TT - 1)) >> 5;
        const size_t base = ((size_t)(b_ * 512 + tile32 * 4)) * 512;  // elems
        const int u = threadIdx.x;                                    // 256 units
        *reinterpret_cast<short8*>(&Kswz[base + (size_t)u * 8]) =
            *reinterpret_cast<const short8*>(&Kimg[u * 8]);
        *reinterpret_cast<short8*>(&Vswz[base + (size_t)u * 8]) =
            *reinterpret_cast<const short8*>(&Vimg[u * 8]);
    }
}

// ---------------------------------------------------------------------------
// Kernel 2: flash causal attention — pair blocks, register-direct KV,
// MFMA-based l accumulation + lazy cross-lane max.
// 256 blocks (4 batch x 64 pairs) x 512 thr; 8 KV streams (T ≡ w mod 8),
// 17 visits/wave for every pr (129 = 8*16+1) -> exact balance.
// R8 LESSONS: (1) 2-block co-residency NEVER materializes on this setup
// (Occupancy pinned ~19% across 36KB/64KB LDS shapes) -> split-K reverted:
// it only added 2x merge overhead + partial traffic (48.4 vs R5's <=40.5).
// (2) The per-visit critical path was dominated by 4 dependent cross-lane
// shfl ops (mcur reduce + lsum reduce, ~100+cyc each). THIS ROUND:
//  - lsum via ones-MFMA: l row-sum = mfma(ones_A, pb, o_l) — the MFMA's
//    K-contraction does the cross-quad sum in HW; o_l rescales with o;
//    l_st = o_l[0] at loop end. Replaces 2 serial shfl+add per qh-visit.
//  - lazy max: in-lane 8-value max tree only; cross-lane reduce + rescale
//    ONLY when __any(mloc > m_st+8) fires (identical trigger semantics to
//    defer-max: some lane exceeds <=> some row exceeds). Common path has
//    ZERO cross-lane ops.
// Register-direct KV kept (R8 win): K reload after qh1 QK^T, V after qh1 PV.
// ---------------------------------------------------------------------------
__global__ __launch_bounds__(512, 2) void attn(
    const bf16* __restrict__ Qb, const bf16* __restrict__ Kswz,
    const bf16* __restrict__ Vswz, const float* __restrict__ rel,
    float* __restrict__ out)
{
    __shared__ __align__(16) float smem[9216];   // 36 KB: Osh 4x32x68 + mM/lL

    const int w     = threadIdx.x >> 6;          // 0..7
    const int lane  = threadIdx.x & 63;
    const int quad  = lane >> 4;
    const int l16   = lane & 15;
    const int batch = blockIdx.x & 3;
    const int pr    = blockIdx.x >> 2;           // 0..63

    const float SCL = 0.125f * LOG2E;
    float relreg = 0.f;
    if (lane < NRE) relreg = rel[lane] * LOG2E;
    const float rel0 = __shfl(relreg, 0, 64);

    const size_t bbase = (size_t)batch * TT;

    float* Osh = smem;                           // 4 slots x [32 rows][68]
    float* mM  = Osh + 4 * 32 * 68;              // 256 (8 streams x 32 rows)
    float* lL  = mM + 256;

    const unsigned loff = (unsigned)lane * 8;    // elems within 512-elem unit row

    short4v ones4;                               // bf16 1.0 x4 (A-frag of ones-MFMA)
    ones4[0] = ones4[1] = ones4[2] = ones4[3] = (short)0x3F80;

#pragma unroll 1
    for (int ph = 0; ph < 2; ph++) {
        const int t  = ph ? (127 - pr) : pr;
        const int q0 = 32 * t;

        short8 bq[2][2];
#pragma unroll
        for (int qh = 0; qh < 2; qh++) {
            const bf16* qp = &Qb[(bbase + q0 + 16 * qh + l16) * DH];
            bq[qh][0] = load8(qp + quad * 8);
            bq[qh][1] = load8(qp + 32 + quad * 8);
        }

        float4v o[2][4];
        float4v o_l[2];                          // ones-MFMA l accumulator
#pragma unroll
        for (int qh = 0; qh < 2; qh++) {
            o_l[qh] = (float4v)(0.f);
#pragma unroll
            for (int dt = 0; dt < 4; dt++) o[qh][dt] = (float4v)(0.f);
        }
        float m_st[2] = {-1e30f, -1e30f};

        const int cnt = (t >= w) ? (((t - w) >> 3) + 1) : 0;

        short8 K0, K1, K2, K3, V0, V1, V2, V3;
        if (cnt > 0) {
            const bf16* kp = Kswz + ((size_t)(batch * 512 + w * 4)) * 512 + loff;
            const bf16* vp = Vswz + ((size_t)(batch * 512 + w * 4)) * 512 + loff;
            K0 = load8(kp);        K1 = load8(kp + 512);
            K2 = load8(kp + 1024); K3 = load8(kp + 1536);
            V0 = load8(vp);        V1 = load8(vp + 512);
            V2 = load8(vp + 1024); V3 = load8(vp + 1536);
        }

        for (int k = 0; k < cnt; k++) {
            const int T  = w + 8 * k;
            const int js = 32 * T;
#pragma unroll
            for (int qh = 0; qh < 2; qh++) {
                float4v st[2];
                st[0] = (float4v)(0.f); st[1] = (float4v)(0.f);
                __builtin_amdgcn_s_setprio(1);
                st[0] = __builtin_amdgcn_mfma_f32_16x16x32_bf16(K0, bq[qh][0], st[0], 0, 0, 0);
                st[0] = __builtin_amdgcn_mfma_f32_16x16x32_bf16(K1, bq[qh][1], st[0], 0, 0, 0);
                st[1] = __builtin_amdgcn_mfma_f32_16x16x32_bf16(K2, bq[qh][0], st[1], 0, 0, 0);
                st[1] = __builtin_amdgcn_mfma_f32_16x16x32_bf16(K3, bq[qh][1], st[1], 0, 0, 0);
                __builtin_amdgcn_s_setprio(0);

                // K consumed for this tile after qh==1: prefetch next tile's K
                if (qh == 1 && k + 1 < cnt) {
                    const bf16* kp = Kswz + ((size_t)(batch * 512 + (T + 8) * 4)) * 512 + loff;
                    K0 = load8(kp);        K1 = load8(kp + 512);
                    K2 = load8(kp + 1024); K3 = load8(kp + 1536);
                }

                const int i_row = q0 + 16 * qh + l16;
                if (js + 40 <= q0 + 16 * qh) {       // interior: bias=rel0, no mask
#pragma unroll
                    for (int n = 0; n < 2; n++)
#pragma unroll
                        for (int r = 0; r < 4; r++)
                            st[n][r] = st[n][r] * SCL + rel0;
                } else {
#pragma unroll
                    for (int n = 0; n < 2; n++) {
                        const int jb = js + 16 * n + 4 * quad;
#pragma unroll
                        for (int r = 0; r < 4; r++) {
                            const int d = jb + r - i_row;
                            int idx = d + 8;
                            idx = idx < 0 ? 0 : (idx > 16 ? 16 : idx);
                            float v = st[n][r] * SCL + __shfl(relreg, idx, 64);
                            st[n][r] = (d > 0) ? -1e30f : v;
                        }
                    }
                }

                // in-lane max tree (no cross-lane in common path)
                const float m01 = fmaxf(fmaxf(st[0][0], st[0][1]), fmaxf(st[0][2], st[0][3]));
                const float m23 = fmaxf(fmaxf(st[1][0], st[1][1]), fmaxf(st[1][2], st[1][3]));
                const float mloc = fmaxf(m01, m23);

                // lazy defer-max: cross-lane reduce + rescale only on trigger
                if (__any(mloc > m_st[qh] + 8.f)) {
                    float mrow = fmaxf(mloc, __shfl_xor(mloc, 16, 64));
                    mrow = fmaxf(mrow, __shfl_xor(mrow, 32, 64));
                    const float mn = fmaxf(m_st[qh], mrow);
                    const float alpha = exp2f(m_st[qh] - mn);
                    m_st[qh] = mn;
#pragma unroll
                    for (int dt = 0; dt < 4; dt++)
#pragma unroll
                        for (int r = 0; r < 4; r++) o[qh][dt][r] *= alpha;
#pragma unroll
                    for (int r = 0; r < 4; r++) o_l[qh][r] *= alpha;
                }
                const float mn = m_st[qh];

                short4v pb[2];
#pragma unroll
                for (int n = 0; n < 2; n++)
#pragma unroll
                    for (int r = 0; r < 4; r++)
                        pb[n][r] = bfbits(exp2f(st[n][r] - mn));

                __builtin_amdgcn_s_setprio(1);
#pragma unroll
                for (int n = 0; n < 2; n++) {
                    // l row-sum via ones-MFMA (HW cross-quad contraction)
                    o_l[qh] = __builtin_amdgcn_mfma_f32_16x16x16bf16_1k(ones4, pb[n], o_l[qh], 0, 0, 0);
#pragma unroll
                    for (int dh = 0; dh < 2; dh++) {
                        const short8 vs = (dh == 0) ? ((n == 0) ? V0 : V2)
                                                    : ((n == 0) ? V1 : V3);
                        short4v lo, hi;
                        lo[0] = vs[0]; lo[1] = vs[1]; lo[2] = vs[2]; lo[3] = vs[3];
                        hi[0] = vs[4]; hi[1] = vs[5]; hi[2] = vs[6]; hi[3] = vs[7];
                        o[qh][2 * dh]     = __builtin_amdgcn_mfma_f32_16x16x16bf16_1k(lo, pb[n], o[qh][2 * dh], 0, 0, 0);
                        o[qh][2 * dh + 1] = __builtin_amdgcn_mfma_f32_16x16x16bf16_1k(hi, pb[n], o[qh][2 * dh + 1], 0, 0, 0);
                    }
                }
                __builtin_amdgcn_s_setprio(0);

                // V consumed for this tile after qh==1: prefetch next tile's V
                if (qh == 1 && k + 1 < cnt) {
                    const bf16* vp = Vswz + ((size_t)(batch * 512 + (T + 8) * 4)) * 512 + loff;
                    V0 = load8(vp);        V1 = load8(vp + 512);
                    V2 = load8(vp + 1024); V3 = load8(vp + 1536);
                }
            }
        }

        float l_st[2];
        l_st[0] = o_l[0][0];   // all 4 components equal (rows of ones-MFMA output)
        l_st[1] = o_l[1][0];

        // ---- hierarchical merge: 8 -> 4 -> 1 (all f32, no o-liveness stack) ----
        __syncthreads();                          // prior phase's merge reads done
        if (w >= 4) {                             // pass 1: high waves retire o NOW
            const int slot = w - 4;
#pragma unroll
            for (int qh = 0; qh < 2; qh++) {
                const int row = 16 * qh + l16;    // 0..31 within slot
                if (quad == 0) { mM[w * 32 + row] = m_st[qh]; lL[w * 32 + row] = l_st[qh]; }
#pragma unroll
                for (int dt = 0; dt < 4; dt++)
                    *reinterpret_cast<float4v*>(&Osh[(slot * 32 + row) * 68 + 16 * dt + 4 * quad]) = o[qh][dt];
            }
        }
        __syncthreads();
        if (w < 4) {                              // pass 2: fold partner into regs
#pragma unroll
            for (int qh = 0; qh < 2; qh++) {
                const int row = 16 * qh + l16;
                const float mp = mM[(w + 4) * 32 + row], lp = lL[(w + 4) * 32 + row];
                const float M  = fmaxf(m_st[qh], mp);
                const float ea = exp2f(m_st[qh] - M);
                const float eb = exp2f(mp - M);
                const float ln = l_st[qh] * ea + lp * eb;
#pragma unroll
                for (int dt = 0; dt < 4; dt++) {
                    float4v op = *reinterpret_cast<float4v*>(&Osh[(w * 32 + row) * 68 + 16 * dt + 4 * quad]);
#pragma unroll
                    for (int r = 0; r < 4; r++) o[qh][dt][r] = o[qh][dt][r] * ea + op[r] * eb;
                }
                if (quad == 0) { mM[w * 32 + row] = M; lL[w * 32 + row] = ln; }
#pragma unroll
                for (int dt = 0; dt < 4; dt++)
                    *reinterpret_cast<float4v*>(&Osh[(w * 32 + row) * 68 + 16 * dt + 4 * quad]) = o[qh][dt];
            }
        }
        __syncthreads();
        {                                         // pass 3: 4-slot final merge
            for (int idx = threadIdx.x; idx < 32 * 64; idx += 512) {
                const int row = idx >> 6;
                const int col = idx & 63;
                float M = mM[row];
#pragma unroll
                for (int s = 1; s < 4; s++) M = fmaxf(M, mM[s * 32 + row]);
                float L = 0.f, a = 0.f;
#pragma unroll
                for (int s = 0; s < 4; s++) {
                    const float ex = exp2f(mM[s * 32 + row] - M);
                    L += lL[s * 32 + row] * ex;
                    a += Osh[(s * 32 + row) * 68 + col] * ex;
                }
                out[(bbase + q0 + row) * DH + col] = a / L;
            }
        }
        __syncthreads();   // merge reads done before next phase reuses smem
    }
}

// ---------------------------------------------------------------------------
extern "C" void kernel_launch(void* const* d_in, const int* in_sizes, int n_in,
                              void* d_out, int out_size, void* d_ws, size_t ws_size,
                              hipStream_t stream)
{
    const float* x   = (const float*)d_in[0];
    const float* Wq  = (const float*)d_in[1];
    const float* Wk  = (const float*)d_in[2];
    const float* Wv  = (const float*)d_in[3];
    const float* rel = (const float*)d_in[4];
    float* out = (float*)d_out;

    bf16* Qb   = (bf16*)d_ws;                         // [B*T,64]        2 MB
    bf16* Kswz = Qb   + (size_t)BT * TT * DH;         // frag-ordered    2 MB
    bf16* Vswz = Kswz + (size_t)BT * TT * DH;         // frag-ordered    2 MB
    bf16* Wswz = Vswz + (size_t)BT * TT * DH;         // swizzled W    384 KB

    w_prep<<<96, 256, 0, stream>>>(Wq, Wk, Wv, Wswz);
    qkv_gemm<<<512, 256, 0, stream>>>(x, Wswz, Qb, Kswz, Vswz);
    attn<<<256, 512, 0, stream>>>(Qb, Kswz, Vswz, rel, out);
}